// Round 11
// baseline (3541.729 us; speedup 1.0000x reference)
//
#include <hip/hip_runtime.h>

typedef __bf16 bf16;
typedef bf16 bf16x8 __attribute__((ext_vector_type(8)));
typedef bf16 bf16x4 __attribute__((ext_vector_type(4)));
typedef float f32x4 __attribute__((ext_vector_type(4)));

#define NB 256
#define TS 64
#define DD 1024
#define HH 1024
#define NOUT 4096
#define NWG 512

// Column permutation (all weight/preact tensors): cx = (h>>4)*64 + (h&15)*4 + g
// (original col co = g*1024 + h). wg "ht" owns cx in [ht*64,+64) = 16 h x 4
// gates; cell thread (n,hl) reads its 4 gates as ONE bf16x4.
// Fragment tiles: 16col x 32k of 512 bf16; element (l,j): col=base+(l&15),
// k=kbase+(l>>4)*8+j (mfma_16x16x32 operand layout; linear LDS staging).

static __device__ __forceinline__ void gload_lds16(const void* g, void* l) {
  __builtin_amdgcn_global_load_lds(
      (const __attribute__((address_space(1))) void*)g,
      (__attribute__((address_space(3))) void*)l, 16, 0, 0);
}

// device-coherent (agent-scope, L2-bypassing) relaxed accesses for data that
// crosses workgroups between persistent-kernel steps. NO fences anywhere --
// ordering comes from explicit vmcnt drains in gsync (R5 lesson: agent
// acquire/release fences invalidate whole L2s and refetch everything).
static __device__ __forceinline__ unsigned long long cload64(const bf16* p) {
  return __hip_atomic_load((const unsigned long long*)p, __ATOMIC_RELAXED,
                           __HIP_MEMORY_SCOPE_AGENT);
}
static __device__ __forceinline__ float cloadf(const float* p) {
  return __hip_atomic_load(p, __ATOMIC_RELAXED, __HIP_MEMORY_SCOPE_AGENT);
}
static __device__ __forceinline__ void cstoref(float* p, float v) {
  __hip_atomic_store(p, v, __ATOMIC_RELAXED, __HIP_MEMORY_SCOPE_AGENT);
}
static __device__ __forceinline__ void cstore32(bf16* p, unsigned v) {
  __hip_atomic_store((unsigned*)p, v, __ATOMIC_RELAXED, __HIP_MEMORY_SCOPE_AGENT);
}

#define SWZ_ADD(v, imm) \
  (v) += __int_as_float(__builtin_amdgcn_ds_swizzle(__float_as_int(v), imm))
#define SWZ_MAX(v, imm) \
  (v) = fmaxf(v, __int_as_float(__builtin_amdgcn_ds_swizzle(__float_as_int(v), imm)))

// ---- one-time converts (unchanged from R10) ---------------------------------
__global__ __launch_bounds__(256) void convert_bf(const float* __restrict__ in,
                                                  bf16* __restrict__ o) {
  const size_t gid = (size_t)blockIdx.x * 256 + threadIdx.x;
  bf16x8 v;
#pragma unroll
  for (int j = 0; j < 8; ++j) v[j] = (bf16)in[gid * 8 + j];
  *(bf16x8*)(o + gid * 8) = v;
}

__global__ __launch_bounds__(256) void convert_wt(const float* __restrict__ W,
                                                  bf16* __restrict__ Wt) {
  const int gid = blockIdx.x * 256 + threadIdx.x;
  const int tile = gid >> 6, l = gid & 63;  // tile = tau*32 + kt
  const int tau = tile >> 5, kt = tile & 31;
  const int cx = tau * 16 + (l & 15);
  const int ht = cx >> 6, rem = cx & 63;
  const int co = (rem & 3) * HH + ht * 16 + (rem >> 2);  // g*1024 + h
  const int k0 = kt * 32 + (l >> 4) * 8;
  bf16x8 o;
#pragma unroll
  for (int j = 0; j < 8; ++j) o[j] = (bf16)W[(size_t)(k0 + j) * NOUT + co];
  *(bf16x8*)(Wt + (size_t)tile * 512 + l * 8) = o;
}

__global__ __launch_bounds__(1024) void transpose_A(const float* __restrict__ A,
                                                    bf16* __restrict__ At) {
  __shared__ float lt[1024 * 17];
  const int n = blockIdx.x, u = threadIdx.x;
  const float* ar = A + ((size_t)n * HH + u) * 16;
#pragma unroll
  for (int q = 0; q < 4; ++q) {
    f32x4 v = *(const f32x4*)(ar + q * 4);
#pragma unroll
    for (int r = 0; r < 4; ++r) lt[u * 17 + q * 4 + r] = v[r];
  }
  __syncthreads();
  const int p = u >> 6, seg = u & 63;
  bf16x8 o0, o1;
#pragma unroll
  for (int j = 0; j < 8; ++j) {
    o0[j] = (bf16)lt[(seg * 16 + j) * 17 + p];
    o1[j] = (bf16)lt[(seg * 16 + 8 + j) * 17 + p];
  }
  bf16* dst = At + (size_t)(n * 16 + p) * 1024 + seg * 16;
  *(bf16x8*)dst = o0;
  *(bf16x8*)(dst + 8) = o1;
}

// ---- 128x128 / BK=32 GEMM (m97 structure), bf16 out (unchanged) -------------
__global__ __launch_bounds__(256, 3) void gemm128(const bf16* __restrict__ Am,
                                                  const bf16* __restrict__ Bt,
                                                  bf16* __restrict__ C) {
  __shared__ __align__(16) bf16 astg[2][8 * 512];
  __shared__ __align__(16) bf16 bstg[2][8 * 512];
  const int b = blockIdx.x;
  const int ct = (b & 7) * 4 + ((b >> 3) & 3);
  const int rt = b >> 5;
  const int tid = threadIdx.x, lane = tid & 63, wid = tid >> 6;
  const int wr = wid >> 1, wc = wid & 1;

  const bf16* gA[2];
  const bf16* gB[2];
  int lA[2], lB[2];
#pragma unroll
  for (int e = 0; e < 2; ++e) {
    const int mt = wid * 2 + e;
    gA[e] = Am + (size_t)(rt * 128 + mt * 16 + (lane & 15)) * 1024 + (lane >> 4) * 8;
    lA[e] = mt * 512;
    gB[e] = Bt + ((size_t)(ct * 8 + mt) * 32) * 512 + lane * 8;
    lB[e] = mt * 512;
  }
  f32x4 acc[4][4];
#pragma unroll
  for (int i = 0; i < 4; ++i)
#pragma unroll
    for (int j = 0; j < 4; ++j) acc[i][j] = (f32x4){0, 0, 0, 0};

#pragma unroll
  for (int e = 0; e < 2; ++e) {
    gload_lds16(gA[e], &astg[0][lA[e]]);
    gload_lds16(gB[e], &bstg[0][lB[e]]);
  }
  for (int it = 0; it < 32; ++it) {
    __syncthreads();
    if (it < 31) {
#pragma unroll
      for (int e = 0; e < 2; ++e) {
        gload_lds16(gA[e] + (it + 1) * 32, &astg[(it + 1) & 1][lA[e]]);
        gload_lds16(gB[e] + (size_t)(it + 1) * 512, &bstg[(it + 1) & 1][lB[e]]);
      }
    }
    const bf16* ab = astg[it & 1];
    const bf16* bb = bstg[it & 1];
    bf16x8 af[4], bfr[4];
#pragma unroll
    for (int i = 0; i < 4; ++i) af[i] = *(const bf16x8*)(ab + (wr * 4 + i) * 512 + lane * 8);
#pragma unroll
    for (int j = 0; j < 4; ++j) bfr[j] = *(const bf16x8*)(bb + (wc * 4 + j) * 512 + lane * 8);
#pragma unroll
    for (int i = 0; i < 4; ++i)
#pragma unroll
      for (int j = 0; j < 4; ++j)
        acc[i][j] = __builtin_amdgcn_mfma_f32_16x16x32_bf16(af[i], bfr[j], acc[i][j], 0, 0, 0);
  }
#pragma unroll
  for (int i = 0; i < 4; ++i)
#pragma unroll
    for (int j = 0; j < 4; ++j) {
      const int row0 = rt * 128 + wr * 64 + i * 16 + (lane >> 4) * 4;
      const int col = ct * 128 + wc * 64 + j * 16 + (lane & 15);
#pragma unroll
      for (int r = 0; r < 4; ++r)
        C[(size_t)(row0 + r) * NOUT + col] = (bf16)acc[i][j][r];
    }
}

// ---- init: h0 = mean(A); c0 = h0; Aop0 = h0; s0[n][p] = full score ----------
__global__ __launch_bounds__(1024) void init_kernel(const float* __restrict__ A,
                                                    float* __restrict__ c_ws,
                                                    bf16* __restrict__ Aop0,
                                                    float* __restrict__ s0) {
  __shared__ float h_sh[1024];
  __shared__ float scA[16], scB[16];
  const int n = (blockIdx.x & 7) * 32 + (blockIdx.x >> 3);
  const int u = threadIdx.x;
  const float* arow = A + ((size_t)n * HH + u) * 16;
  float h0 = 0.f;
#pragma unroll
  for (int p = 0; p < 16; ++p) h0 += arow[p];
  h0 *= 0.0625f;
  c_ws[(n << 10) + u] = h0;
  h_sh[u] = h0;
  Aop0[(n << 10) + u] = (bf16)h0;
  __syncthreads();
  const int lane = u & 63, w = u >> 6;  // wave w owns position p=w
  const float* ap = A + (size_t)n * (HH * 16) + w;
  float s = 0.f;
#pragma unroll
  for (int i = 0; i < 16; ++i) {
    const int idx = lane + 64 * i;
    s = fmaf(h_sh[idx], ap[(size_t)idx * 16], s);
  }
  SWZ_ADD(s, 0x041F); SWZ_ADD(s, 0x081F); SWZ_ADD(s, 0x101F);
  SWZ_ADD(s, 0x201F); SWZ_ADD(s, 0x401F);
  if (lane == 0) scA[w] = s;
  else if (lane == 32) scB[w] = s;
  __syncthreads();
  if (u < 16) s0[n * 16 + u] = scA[u] + scB[u];
}

// ---- persistent sequence kernel: 64 steps, 1 grid-sync per step -------------
// wg (rt,ht): 32 n x (16 h x 4 gates). 8 waves = 4 kg x 2 col-halves.
// Cross-step exchange: Aop h (coherent stores/loads), scores via atomicAdd
// into a 3-rotating buffer (zero-one-ahead). c lives in a register. G rows
// preloaded into 32 VGPRs once (kills the 32 MB/step G stream).
#define SEQ_SMEM 65536
__global__ __launch_bounds__(512, 4) void seq_kernel(
    bf16* Aop0, bf16* Aop1, const bf16* __restrict__ Wh_t,
    const bf16* __restrict__ xWx, const bf16* __restrict__ G,
    float* s0, float* s1, float* s2, const float* __restrict__ bias,
    const bf16* __restrict__ A_bf, const float* __restrict__ c0_ws,
    float* __restrict__ out, unsigned* bar_cnt, unsigned* bar_gen) {
  __shared__ __align__(16) char smem[SEQ_SMEM];  // astg 64 KB / red union
  __shared__ float w_sh[512];
  bf16* astg = (bf16*)smem;
  float* red = (float*)smem;

  const int b = blockIdx.x;
  const int xcd = b & 7;
  const int ht = xcd * 8 + ((b >> 3) & 7);  // [0,64)
  const int rt = b >> 6;                    // [0,8)
  const int tid = threadIdx.x, lane = tid & 63, wid = tid >> 6;
  const int kg = wid >> 1, ow = wid & 1;
  const int nloc = tid >> 4, hl = tid & 15;
  const int n = rt * 32 + nloc, h = ht * 16 + hl;

  // ---- one-time preloads (live across all 64 steps) ----
  bf16x4 gq[16];  // G rows: step-invariant! 32 VGPRs
  {
    const bf16* Gp = G + ((size_t)n * 16) * NOUT + ht * 64 + hl * 4;
#pragma unroll
    for (int p = 0; p < 16; ++p) gq[p] = *(const bf16x4*)(Gp + (size_t)p * NOUT);
  }
  const float bi = bias[h], bfg = bias[HH + h], bo = bias[2 * HH + h], bg = bias[3 * HH + h];
  bf16x8 av0, av1;  // A row for score partials (step-invariant)
  {
    const bf16* ar = A_bf + ((size_t)n * HH + h) * 16;
    av0 = *(const bf16x8*)ar;
    av1 = *(const bf16x8*)(ar + 8);
  }
  float creg = c0_ws[(n << 10) + h];  // c state in register

  // A-staging geometry: wave (kg,ow) stages row-block mt=ow of its kg.
  const int abase = (rt * 32 + ow * 16 + (lane & 15)) * 1024 + kg * 256 + (lane >> 4) * 8;
  const int lbase = kg * 8192 + ow * 8 * 512 + lane * 8;
  // B pointers (constant across steps): taus ht*4 + ow*2 + j, 8 ktiles each.
  const bf16* gB0 = Wh_t + ((size_t)(ht * 4 + ow * 2 + 0) * 32 + kg * 8) * 512 + lane * 8;
  const bf16* gB1 = Wh_t + ((size_t)(ht * 4 + ow * 2 + 1) * 32 + kg * 8) * 512 + lane * 8;

  unsigned bar = 0;
  for (int t = 0; t < TS; ++t) {
    bf16* Acur = (t & 1) ? Aop1 : Aop0;
    bf16* Anxt = (t & 1) ? Aop0 : Aop1;
    const int m3 = t % 3;
    float* sb_cur = (m3 == 0) ? s0 : (m3 == 1) ? s1 : s2;
    float* sb_nxt = (m3 == 0) ? s1 : (m3 == 1) ? s2 : s0;
    float* sb_zro = (m3 == 0) ? s2 : (m3 == 1) ? s0 : s1;

    // single-shot A staging: coherent 16B/lane x 8 tiles -> LDS (linear)
#pragma unroll
    for (int i = 0; i < 8; ++i) {
      const unsigned long long q0 = cload64(Acur + abase + i * 32);
      const unsigned long long q1 = cload64(Acur + abase + i * 32 + 4);
      unsigned long long* d = (unsigned long long*)(astg + lbase + i * 512);
      d[0] = q0;
      d[1] = q1;
    }
    // xWx slice for this step (plain cached; streamed once over the run)
    const bf16x4 xv = *(const bf16x4*)(xWx + ((size_t)(n * TS + t)) * NOUT + ht * 64 + hl * 4);
    // zero the buffer that step t+1 will accumulate into t+2's scores
    if (t < TS - 2 && tid < 8) cstoref(&sb_zro[b * 8 + tid], 0.f);
    // softmax over p (16-lane groups); hides under the staging latency
    {
      float ss = cloadf(&sb_cur[n * 16 + hl]) * 0.03125f;  // 1/sqrt(1024)
      float m = ss;
      SWZ_MAX(m, 0x041F); SWZ_MAX(m, 0x081F); SWZ_MAX(m, 0x101F); SWZ_MAX(m, 0x201F);
      const float e = expf(ss - m);
      float su = e;
      SWZ_ADD(su, 0x041F); SWZ_ADD(su, 0x081F); SWZ_ADD(su, 0x101F); SWZ_ADD(su, 0x201F);
      w_sh[tid] = e / su;
    }
    __syncthreads();  // staging ds_writes visible (single vmcnt/lgkm drain)

    // ---- GEMM: 32 MFMA/wave over K=256 slice, B rolling 1-ahead ----
    f32x4 a00 = {0, 0, 0, 0}, a01 = {0, 0, 0, 0}, a10 = {0, 0, 0, 0}, a11 = {0, 0, 0, 0};
    {
      const bf16* ab = astg + kg * 8192;
      bf16x8 bc0 = *(const bf16x8*)gB0;
      bf16x8 bc1 = *(const bf16x8*)gB1;
#pragma unroll
      for (int ks = 0; ks < 8; ++ks) {
        bf16x8 bn0, bn1;
        if (ks < 7) {
          bn0 = *(const bf16x8*)(gB0 + (ks + 1) * 512);
          bn1 = *(const bf16x8*)(gB1 + (ks + 1) * 512);
        }
        const bf16x8 f0 = *(const bf16x8*)(ab + (0 * 8 + ks) * 512 + lane * 8);
        const bf16x8 f1 = *(const bf16x8*)(ab + (1 * 8 + ks) * 512 + lane * 8);
        a00 = __builtin_amdgcn_mfma_f32_16x16x32_bf16(f0, bc0, a00, 0, 0, 0);
        a01 = __builtin_amdgcn_mfma_f32_16x16x32_bf16(f0, bc1, a01, 0, 0, 0);
        a10 = __builtin_amdgcn_mfma_f32_16x16x32_bf16(f1, bc0, a10, 0, 0, 0);
        a11 = __builtin_amdgcn_mfma_f32_16x16x32_bf16(f1, bc1, a11, 0, 0, 0);
        if (ks < 7) { bc0 = bn0; bc1 = bn1; }
      }
    }
    __syncthreads();  // astg reads done -> red region live

    // fragment -> red[(kg*64 + c)*36 + nn]; c = ow*32 + j*16 + (lane&15)
    {
      const int cb = kg * 64 + ow * 32 + (lane & 15);
      const int nb = (lane >> 4) * 4;
      *(f32x4*)&red[(cb)*36 + nb] = a00;
      *(f32x4*)&red[(cb + 16) * 36 + nb] = a01;
      *(f32x4*)&red[(cb)*36 + nb + 16] = a10;
      *(f32x4*)&red[(cb + 16) * 36 + nb + 16] = a11;
    }
    __syncthreads();

    // ---- cell ----
    f32x4 gv = {0, 0, 0, 0};
#pragma unroll
    for (int k2 = 0; k2 < 4; ++k2)
#pragma unroll
      for (int g = 0; g < 4; ++g) gv[g] += red[(k2 * 64 + hl * 4 + g) * 36 + nloc];
#pragma unroll
    for (int p = 0; p < 16; ++p) {
      const float wv = w_sh[nloc * 16 + p];
      gv[0] = fmaf(wv, (float)gq[p][0], gv[0]);
      gv[1] = fmaf(wv, (float)gq[p][1], gv[1]);
      gv[2] = fmaf(wv, (float)gq[p][2], gv[2]);
      gv[3] = fmaf(wv, (float)gq[p][3], gv[3]);
    }
    const float ai = gv[0] + (float)xv[0] + bi;
    const float af = gv[1] + (float)xv[1] + bfg;
    const float ao = gv[2] + (float)xv[2] + bo;
    const float ag = gv[3] + (float)xv[3] + bg;
    const float si = 1.f / (1.f + expf(-ai));
    const float sf = 1.f / (1.f + expf(-af));
    const float so = 1.f / (1.f + expf(-ao));
    const float cn = sf * creg + si * tanhf(ag);
    const float hn = so * tanhf(cn);
    creg = cn;
    out[((size_t)n * TS + t) * HH + h] = hn;  // plain (flushed at kernel end)
    // coherent h write, packed 2 per u32 (even hl stores both)
    {
      const float pn = __shfl_down(hn, 1, 64);
      if ((hl & 1) == 0) {
        const bf16 lo = (bf16)hn, hi = (bf16)pn;
        const unsigned pv = (unsigned)*(const unsigned short*)&lo |
                            ((unsigned)*(const unsigned short*)&hi << 16);
        cstore32(&Anxt[(n << 10) + h], pv);
      }
    }

    if (t < TS - 1) {  // next-step score partials: LDS transpose + atomicAdd
      __syncthreads();  // red gate-reads done -> reuse as transpose buffer
#pragma unroll
      for (int r = 0; r < 8; ++r) {
        red[(nloc * 16 + r) * 17 + hl] = hn * (float)av0[r];
        red[(nloc * 16 + 8 + r) * 17 + hl] = hn * (float)av1[r];
      }
      __syncthreads();
      const float* r2 = &red[(nloc * 16 + hl) * 17];  // p = hl, sum 16 h
      float s = 0.f;
#pragma unroll
      for (int q = 0; q < 16; ++q) s += r2[q];
      atomicAdd(&sb_nxt[n * 16 + hl], s);  // device-scope [m20]
    }

    // ---- grid sync: vmcnt drain + relaxed counter (NO fences) ----
    __syncthreads();
    if (tid == 0) {
      ++bar;
      asm volatile("s_waitcnt vmcnt(0) lgkmcnt(0)" ::: "memory");
      const unsigned arrived = __hip_atomic_fetch_add(bar_cnt, 1u, __ATOMIC_RELAXED,
                                                      __HIP_MEMORY_SCOPE_AGENT);
      if (arrived == NWG - 1) {
        __hip_atomic_store(bar_cnt, 0u, __ATOMIC_RELAXED, __HIP_MEMORY_SCOPE_AGENT);
        asm volatile("s_waitcnt vmcnt(0)" ::: "memory");
        __hip_atomic_store(bar_gen, bar, __ATOMIC_RELAXED, __HIP_MEMORY_SCOPE_AGENT);
      } else {
        while (__hip_atomic_load(bar_gen, __ATOMIC_RELAXED, __HIP_MEMORY_SCOPE_AGENT) < bar)
          __builtin_amdgcn_s_sleep(2);
      }
    } else if (lane == 0) {
      ++bar;  // keep bar consistent on all threads (it's per-thread anyway)
    } else {
      ++bar;
    }
    __syncthreads();
  }
}

// ---------------------------------------------------------------------------
// ws layout (bytes), ~245 MB of 256 MiB:
//   [0, 8388608)             Wh_t   bf16 tiles (1024x4096, cx cols)
//   [8388608, 16777216)      Wat_t  bf16 tiles (1024x4096, cx cols)
//   [16777216, 25165824)     At     bf16 (4096x1024)
//   [25165824, 33554432)     A_bf   bf16 (256x1024x16)
//   [33554432, 167772160)    xWx    bf16 (16384x4096, cx cols)
//   [167772160, 201326592)   G      bf16 (4096x4096, cx cols)
//   [201326592, 234881024)   x_bf   bf16 (16384x1024)  [transient]
//   [234881024, 243269632)   Wxt    bf16 tiles         [transient]
//   [243269632, 243793920)   Aop0   bf16 (256x1024)
//   [243793920, 244318208)   Aop1   bf16 (256x1024)
//   [244318208, 244334592)   s0     f32 (256x16)
//   [244334592, 244350976)   s1     f32 (256x16)   [memset 0 each call]
//   [244350976, 244367360)   s2     f32 (256x16)
//   [244367360, 245415936)   c_ws   f32 (256x1024) [init->seq handoff]
//   [245415936, 245415944)   barrier cnt/gen       [memset 0 each call]
// ---------------------------------------------------------------------------
extern "C" void kernel_launch(void* const* d_in, const int* in_sizes, int n_in,
                              void* d_out, int out_size, void* d_ws, size_t ws_size,
                              hipStream_t stream) {
  const float* x     = (const float*)d_in[0];
  const float* A     = (const float*)d_in[1];
  const float* Wx    = (const float*)d_in[2];
  const float* Wh    = (const float*)d_in[3];
  const float* Wattn = (const float*)d_in[4];
  const float* bias  = (const float*)d_in[5];
  float* out = (float*)d_out;
  char* ws = (char*)d_ws;
  bf16* Wh_t   = (bf16*)(ws + 0);
  bf16* Wat_t  = (bf16*)(ws + 8388608);
  bf16* At     = (bf16*)(ws + 16777216);
  bf16* A_bf   = (bf16*)(ws + 25165824);
  bf16* xWx    = (bf16*)(ws + 33554432);
  bf16* G      = (bf16*)(ws + 167772160);
  bf16* x_bf   = (bf16*)(ws + 201326592);
  bf16* Wxt    = (bf16*)(ws + 234881024);
  bf16* Aop0   = (bf16*)(ws + 243269632);
  bf16* Aop1   = (bf16*)(ws + 243793920);
  float* s0    = (float*)(ws + 244318208);
  float* s1    = (float*)(ws + 244334592);
  float* s2    = (float*)(ws + 244350976);
  float* c_ws  = (float*)(ws + 244367360);
  unsigned* barp = (unsigned*)(ws + 245415936);

  hipMemsetAsync(s1, 0, 16384, stream);
  hipMemsetAsync(barp, 0, 8, stream);
  convert_bf<<<8192, 256, 0, stream>>>(x, x_bf);
  convert_bf<<<2048, 256, 0, stream>>>(A, A_bf);
  convert_wt<<<2048, 256, 0, stream>>>(Wx, Wxt);
  convert_wt<<<2048, 256, 0, stream>>>(Wh, Wh_t);
  convert_wt<<<2048, 256, 0, stream>>>(Wattn, Wat_t);
  gemm128<<<4096, 256, 0, stream>>>(x_bf, Wxt, xWx);  // xWx = x @ Wx
  transpose_A<<<256, 1024, 0, stream>>>(A, At);
  gemm128<<<1024, 256, 0, stream>>>(At, Wat_t, G);    // G = A^T @ Wattn (bf16)
  init_kernel<<<256, 1024, 0, stream>>>(A, c_ws, Aop0, s0);
  seq_kernel<<<NWG, 512, 0, stream>>>(Aop0, Aop1, Wh_t, xWx, G, s0, s1, s2,
                                      bias, A_bf, c_ws, out, barp, barp + 1);
}

// Round 12
// 1404.384 us; speedup vs baseline: 2.5219x; 2.5219x over previous
//
#include <hip/hip_runtime.h>

typedef __bf16 bf16;
typedef bf16 bf16x8 __attribute__((ext_vector_type(8)));
typedef bf16 bf16x4 __attribute__((ext_vector_type(4)));
typedef float f32x4 __attribute__((ext_vector_type(4)));

#define NB 256
#define TS 64
#define DD 1024
#define HH 1024
#define NOUT 4096

// Column permutation (all weight/preact tensors): cx = (h>>4)*64 + (h&15)*4 + g
// (original col co = g*1024 + h). wg "ht" owns cx in [ht*64,+64) = 16 h x 4
// gates; cell thread (n,hl) reads its 4 gates as ONE bf16x4.
// Fragment tiles: 16col x 32k of 512 bf16; element (l,j): col=base+(l&15),
// k=kbase+(l>>4)*8+j (mfma_16x16x32 operand layout; linear LDS staging).
// Step-readable tensors are laid out for the step kernel's access pattern:
//   xWx2 : [t][n][cx]      (per-step slice = contiguous 2 MB stream)
//   G2   : [n][cx][p]      (per-thread read = contiguous 128 B)

static __device__ __forceinline__ void gload_lds16(const void* g, void* l) {
  __builtin_amdgcn_global_load_lds(
      (const __attribute__((address_space(1))) void*)g,
      (__attribute__((address_space(3))) void*)l, 16, 0, 0);
}

#define SWZ_ADD(v, imm) \
  (v) += __int_as_float(__builtin_amdgcn_ds_swizzle(__float_as_int(v), imm))
#define SWZ_MAX(v, imm) \
  (v) = fmaxf(v, __int_as_float(__builtin_amdgcn_ds_swizzle(__float_as_int(v), imm)))

// ---- one-time converts ------------------------------------------------------
__global__ __launch_bounds__(256) void convert_bf(const float* __restrict__ in,
                                                  bf16* __restrict__ o) {
  const size_t gid = (size_t)blockIdx.x * 256 + threadIdx.x;
  bf16x8 v;
#pragma unroll
  for (int j = 0; j < 8; ++j) v[j] = (bf16)in[gid * 8 + j];
  *(bf16x8*)(o + gid * 8) = v;
}

__global__ __launch_bounds__(256) void convert_wt(const float* __restrict__ W,
                                                  bf16* __restrict__ Wt) {
  const int gid = blockIdx.x * 256 + threadIdx.x;
  const int tile = gid >> 6, l = gid & 63;  // tile = tau*32 + kt
  const int tau = tile >> 5, kt = tile & 31;
  const int cx = tau * 16 + (l & 15);
  const int ht = cx >> 6, rem = cx & 63;
  const int co = (rem & 3) * HH + ht * 16 + (rem >> 2);  // g*1024 + h
  const int k0 = kt * 32 + (l >> 4) * 8;
  bf16x8 o;
#pragma unroll
  for (int j = 0; j < 8; ++j) o[j] = (bf16)W[(size_t)(k0 + j) * NOUT + co];
  *(bf16x8*)(Wt + (size_t)tile * 512 + l * 8) = o;
}

__global__ __launch_bounds__(1024) void transpose_A(const float* __restrict__ A,
                                                    bf16* __restrict__ At) {
  __shared__ float lt[1024 * 17];
  const int n = blockIdx.x, u = threadIdx.x;
  const float* ar = A + ((size_t)n * HH + u) * 16;
#pragma unroll
  for (int q = 0; q < 4; ++q) {
    f32x4 v = *(const f32x4*)(ar + q * 4);
#pragma unroll
    for (int r = 0; r < 4; ++r) lt[u * 17 + q * 4 + r] = v[r];
  }
  __syncthreads();
  const int p = u >> 6, seg = u & 63;
  bf16x8 o0, o1;
#pragma unroll
  for (int j = 0; j < 8; ++j) {
    o0[j] = (bf16)lt[(seg * 16 + j) * 17 + p];
    o1[j] = (bf16)lt[(seg * 16 + 8 + j) * 17 + p];
  }
  bf16* dst = At + (size_t)(n * 16 + p) * 1024 + seg * 16;
  *(bf16x8*)dst = o0;
  *(bf16x8*)(dst + 8) = o1;
}

// ---- 128x128 / BK=32 GEMM (m97 structure), bf16 out, epilogue-permuted -----
// MODE 0: rows are (n*TS+t) -> write [t][n][col]   (xWx2)
// MODE 1: rows are (n*16+p) -> write [n][col][p]   (G2)
template <int MODE>
__global__ __launch_bounds__(256, 3) void gemm128(const bf16* __restrict__ Am,
                                                  const bf16* __restrict__ Bt,
                                                  bf16* __restrict__ C) {
  __shared__ __align__(16) bf16 astg[2][8 * 512];
  __shared__ __align__(16) bf16 bstg[2][8 * 512];
  const int b = blockIdx.x;
  const int ct = (b & 7) * 4 + ((b >> 3) & 3);
  const int rt = b >> 5;
  const int tid = threadIdx.x, lane = tid & 63, wid = tid >> 6;
  const int wr = wid >> 1, wc = wid & 1;

  const bf16* gA[2];
  const bf16* gB[2];
  int lA[2], lB[2];
#pragma unroll
  for (int e = 0; e < 2; ++e) {
    const int mt = wid * 2 + e;
    gA[e] = Am + (size_t)(rt * 128 + mt * 16 + (lane & 15)) * 1024 + (lane >> 4) * 8;
    lA[e] = mt * 512;
    gB[e] = Bt + ((size_t)(ct * 8 + mt) * 32) * 512 + lane * 8;
    lB[e] = mt * 512;
  }
  f32x4 acc[4][4];
#pragma unroll
  for (int i = 0; i < 4; ++i)
#pragma unroll
    for (int j = 0; j < 4; ++j) acc[i][j] = (f32x4){0, 0, 0, 0};

#pragma unroll
  for (int e = 0; e < 2; ++e) {
    gload_lds16(gA[e], &astg[0][lA[e]]);
    gload_lds16(gB[e], &bstg[0][lB[e]]);
  }
  for (int it = 0; it < 32; ++it) {
    __syncthreads();
    if (it < 31) {
#pragma unroll
      for (int e = 0; e < 2; ++e) {
        gload_lds16(gA[e] + (it + 1) * 32, &astg[(it + 1) & 1][lA[e]]);
        gload_lds16(gB[e] + (size_t)(it + 1) * 512, &bstg[(it + 1) & 1][lB[e]]);
      }
    }
    const bf16* ab = astg[it & 1];
    const bf16* bb = bstg[it & 1];
    bf16x8 af[4], bfr[4];
#pragma unroll
    for (int i = 0; i < 4; ++i) af[i] = *(const bf16x8*)(ab + (wr * 4 + i) * 512 + lane * 8);
#pragma unroll
    for (int j = 0; j < 4; ++j) bfr[j] = *(const bf16x8*)(bb + (wc * 4 + j) * 512 + lane * 8);
#pragma unroll
    for (int i = 0; i < 4; ++i)
#pragma unroll
      for (int j = 0; j < 4; ++j)
        acc[i][j] = __builtin_amdgcn_mfma_f32_16x16x32_bf16(af[i], bfr[j], acc[i][j], 0, 0, 0);
  }
  // C/D layout: col=lane&15, row=(lane>>4)*4+r [m89-verified]
#pragma unroll
  for (int i = 0; i < 4; ++i)
#pragma unroll
    for (int j = 0; j < 4; ++j) {
      const int row0 = rt * 128 + wr * 64 + i * 16 + (lane >> 4) * 4;
      const int col = ct * 128 + wc * 64 + j * 16 + (lane & 15);
#pragma unroll
      for (int r = 0; r < 4; ++r) {
        const int row = row0 + r;
        size_t idx;
        if (MODE == 0) idx = ((size_t)(row & 63) * NB + (row >> 6)) * NOUT + col;
        else           idx = (size_t)(row >> 4) * (NOUT * 16) + (size_t)col * 16 + (row & 15);
        C[idx] = (bf16)acc[i][j][r];
      }
    }
}

// ---- init: h0 = mean(A); c0 = h0; Aop0 = h0; s0[n*16+p] = full score --------
__global__ __launch_bounds__(1024) void init_kernel(const float* __restrict__ A,
                                                    float* __restrict__ c_ws,
                                                    bf16* __restrict__ Aop0,
                                                    float* __restrict__ s0) {
  __shared__ float h_sh[1024];
  __shared__ float scA[16], scB[16];
  const int n = (blockIdx.x & 7) * 32 + (blockIdx.x >> 3);
  const int u = threadIdx.x;
  const float* arow = A + ((size_t)n * HH + u) * 16;
  float h0 = 0.f;
#pragma unroll
  for (int p = 0; p < 16; ++p) h0 += arow[p];
  h0 *= 0.0625f;
  c_ws[(n << 10) + u] = h0;
  h_sh[u] = h0;
  Aop0[(n << 10) + u] = (bf16)h0;
  __syncthreads();
  const int lane = u & 63, w = u >> 6;  // wave w owns position p=w
  const float* ap = A + (size_t)n * (HH * 16) + w;
  float s = 0.f;
#pragma unroll
  for (int i = 0; i < 16; ++i) {
    const int idx = lane + 64 * i;
    s = fmaf(h_sh[idx], ap[(size_t)idx * 16], s);
  }
  SWZ_ADD(s, 0x041F); SWZ_ADD(s, 0x081F); SWZ_ADD(s, 0x101F);
  SWZ_ADD(s, 0x201F); SWZ_ADD(s, 0x401F);
  if (lane == 0) scA[w] = s;
  else if (lane == 32) scB[w] = s;
  __syncthreads();
  if (u < 16) s0[n * 16 + u] = scA[u] + scB[u];
}

// ---- per-step kernel -------------------------------------------------------
// 512 wgs x 512 thr (2 wg/CU). wg (rt,ht): 32 n x (16 h x 4 gates).
// ONE-SHOT K=1024 staging (64 KB LDS, single vmcnt drain), then 32 MFMA/wave.
// Scores: read s_cur (1 f32), accumulate s_nxt via atomicAdd, zero s_zro
// (3-buffer rotation; no slot re-reads).
#define STEP_SMEM 65536
__global__ __launch_bounds__(512, 4) void step_kernel(
    const bf16* __restrict__ Aop_cur, bf16* __restrict__ Aop_nxt,
    const bf16* __restrict__ Wh_t, const bf16* __restrict__ xWx2,
    const bf16* __restrict__ G2, const float* __restrict__ s_cur,
    float* __restrict__ s_nxt, float* __restrict__ s_zro,
    const float* __restrict__ bias, const bf16* __restrict__ A_bf,
    float* __restrict__ c_ws, float* __restrict__ out, const int t) {
  __shared__ __align__(16) char smem[STEP_SMEM];
  __shared__ float w_sh[512];
  bf16* astg = (bf16*)smem;   // [kg][mt*8+ks][512] = 64 KB (one-shot)
  float* red = (float*)smem;  // union after GEMM

  const int b = blockIdx.x;
  const int xcd = b & 7;
  const int ht = xcd * 8 + ((b >> 3) & 7);  // [0,64)
  const int rt = b >> 6;                    // [0,8)
  const int tid = threadIdx.x, lane = tid & 63, wid = tid >> 6;
  const int kg = wid >> 1, ow = wid & 1;
  const int nloc = tid >> 4, hl = tid & 15;
  const int n = rt * 32 + nloc, h = ht * 16 + hl;

  // score read FIRST (its waitcnt then only covers this one load)
  float ss = s_cur[n * 16 + hl];

  // one-shot A staging: wave wid issues tiles tau = wid*8+e
#pragma unroll
  for (int e = 0; e < 8; ++e) {
    const int tau = wid * 8 + e;
    const int tkg = tau >> 4, tmt = (tau >> 3) & 1, tks = tau & 7;
    const bf16* src = Aop_cur +
        (size_t)(rt * 32 + tmt * 16 + (lane & 15)) * 1024 +
        tkg * 256 + tks * 32 + (lane >> 4) * 8;
    gload_lds16(src, astg + tkg * 8192 + (tmt * 8 + tks) * 512);
  }

  // early-issue (T14): G2 block (128 B contiguous) + xWx2 vector
  bf16x8 gq[8];
  {
    const bf16* Gp = G2 + (size_t)n * (NOUT * 16) + (size_t)(ht * 64 + hl * 4) * 16;
#pragma unroll
    for (int e = 0; e < 8; ++e) gq[e] = *(const bf16x8*)(Gp + e * 8);
  }
  const bf16x4 xv = *(const bf16x4*)(xWx2 + (size_t)t * (NB * NOUT) +
                                     (size_t)n * NOUT + ht * 64 + hl * 4);
  // zero the t+2 score buffer (32 B per wg)
  if (tid < 8) s_zro[b * 8 + tid] = 0.f;

  // softmax over p within 16-lane groups
  {
    ss *= 0.03125f;  // 1/sqrt(1024)
    float m = ss;
    SWZ_MAX(m, 0x041F); SWZ_MAX(m, 0x081F); SWZ_MAX(m, 0x101F); SWZ_MAX(m, 0x201F);
    const float e = expf(ss - m);
    float su = e;
    SWZ_ADD(su, 0x041F); SWZ_ADD(su, 0x081F); SWZ_ADD(su, 0x101F); SWZ_ADD(su, 0x201F);
    w_sh[tid] = e / su;
  }
  __syncthreads();  // single drain: staging + gq + xv all landed

  // ---- GEMM: wave (kg,ow) does K=256, 8 ks x 4 MFMA, B rolling 1-ahead ----
  const bf16* gB0 = Wh_t + ((size_t)(ht * 4 + ow * 2 + 0) * 32 + kg * 8) * 512 + lane * 8;
  const bf16* gB1 = Wh_t + ((size_t)(ht * 4 + ow * 2 + 1) * 32 + kg * 8) * 512 + lane * 8;
  f32x4 a00 = {0, 0, 0, 0}, a01 = {0, 0, 0, 0}, a10 = {0, 0, 0, 0}, a11 = {0, 0, 0, 0};
  {
    const bf16* ab = astg + kg * 8192;
    bf16x8 bc0 = *(const bf16x8*)gB0;
    bf16x8 bc1 = *(const bf16x8*)gB1;
    __builtin_amdgcn_s_setprio(1);
#pragma unroll
    for (int ks = 0; ks < 8; ++ks) {
      bf16x8 bn0, bn1;
      if (ks < 7) {
        bn0 = *(const bf16x8*)(gB0 + (ks + 1) * 512);
        bn1 = *(const bf16x8*)(gB1 + (ks + 1) * 512);
      }
      const bf16x8 f0 = *(const bf16x8*)(ab + ks * 512 + lane * 8);
      const bf16x8 f1 = *(const bf16x8*)(ab + (8 + ks) * 512 + lane * 8);
      a00 = __builtin_amdgcn_mfma_f32_16x16x32_bf16(f0, bc0, a00, 0, 0, 0);
      a01 = __builtin_amdgcn_mfma_f32_16x16x32_bf16(f0, bc1, a01, 0, 0, 0);
      a10 = __builtin_amdgcn_mfma_f32_16x16x32_bf16(f1, bc0, a10, 0, 0, 0);
      a11 = __builtin_amdgcn_mfma_f32_16x16x32_bf16(f1, bc1, a11, 0, 0, 0);
      if (ks < 7) { bc0 = bn0; bc1 = bn1; }
    }
    __builtin_amdgcn_s_setprio(0);
  }
  __syncthreads();  // astg dead -> red live

  // fragment -> red[(kg*64 + c)*36 + nn]; c = ow*32 + j*16 + (lane&15)
  {
    const int cb = kg * 64 + ow * 32 + (lane & 15);
    const int nb = (lane >> 4) * 4;
    *(f32x4*)&red[(cb)*36 + nb] = a00;
    *(f32x4*)&red[(cb + 16) * 36 + nb] = a01;
    *(f32x4*)&red[(cb)*36 + nb + 16] = a10;
    *(f32x4*)&red[(cb + 16) * 36 + nb + 16] = a11;
  }
  __syncthreads();

  // ---- cell ----
  f32x4 gv = {0, 0, 0, 0};
#pragma unroll
  for (int k2 = 0; k2 < 4; ++k2)
#pragma unroll
    for (int g = 0; g < 4; ++g) gv[g] += red[(k2 * 64 + hl * 4 + g) * 36 + nloc];
  // attn term: gv[g] += sum_p w[p] * G2[n][hl*4+g][p];  G2 vals in gq[g*2+ (p>>3)][p&7]
#pragma unroll
  for (int g = 0; g < 4; ++g) {
    float acc = 0.f;
#pragma unroll
    for (int p = 0; p < 8; ++p) acc = fmaf(w_sh[nloc * 16 + p], (float)gq[g * 2][p], acc);
#pragma unroll
    for (int p = 0; p < 8; ++p) acc = fmaf(w_sh[nloc * 16 + 8 + p], (float)gq[g * 2 + 1][p], acc);
    gv[g] += acc;
  }
  const float ai = gv[0] + (float)xv[0] + bias[h];
  const float af = gv[1] + (float)xv[1] + bias[HH + h];
  const float ao = gv[2] + (float)xv[2] + bias[2 * HH + h];
  const float ag = gv[3] + (float)xv[3] + bias[3 * HH + h];
  const float cold = c_ws[(n << 10) + h];
  const float si = 1.f / (1.f + expf(-ai));
  const float sf = 1.f / (1.f + expf(-af));
  const float so = 1.f / (1.f + expf(-ao));
  const float cn = sf * cold + si * tanhf(ag);
  const float hn = so * tanhf(cn);
  c_ws[(n << 10) + h] = cn;
  out[((size_t)n * TS + t) * HH + h] = hn;
  Aop_nxt[(n << 10) + h] = (bf16)hn;

  if (t < TS - 1) {  // next-step score partials: LDS transpose + atomicAdd
    __syncthreads();  // red gate-reads done -> reuse as transpose buffer
    const bf16* arow = A_bf + ((size_t)n * HH + h) * 16;
    const bf16x8 av0 = *(const bf16x8*)arow;
    const bf16x8 av1 = *(const bf16x8*)(arow + 8);
#pragma unroll
    for (int r = 0; r < 8; ++r) {
      red[(nloc * 16 + r) * 17 + hl] = hn * (float)av0[r];
      red[(nloc * 16 + 8 + r) * 17 + hl] = hn * (float)av1[r];
    }
    __syncthreads();
    const float* r2 = &red[(nloc * 16 + hl) * 17];  // p = hl, sum over 16 h
    float s = 0.f;
#pragma unroll
    for (int q = 0; q < 16; ++q) s += r2[q];
    atomicAdd(&s_nxt[n * 16 + hl], s);  // device-scope [m20]
  }
}

// ---------------------------------------------------------------------------
// ws layout (bytes), ~245 MB of 256 MiB:
//   [0, 8388608)             Wh_t   bf16 tiles (1024x4096, cx cols)
//   [8388608, 16777216)      Wat_t  bf16 tiles (1024x4096, cx cols)
//   [16777216, 25165824)     At     bf16 (4096x1024)
//   [25165824, 33554432)     A_bf   bf16 (256x1024x16)
//   [33554432, 167772160)    xWx2   bf16 [t][n][cx] (64x256x4096)
//   [167772160, 201326592)   G2     bf16 [n][cx][p] (256x4096x16)
//   [201326592, 234881024)   x_bf   bf16 (16384x1024)  [transient]
//   [234881024, 243269632)   Wxt    bf16 tiles         [transient]
//   [243269632, 243793920)   Aop0   bf16 (256x1024)
//   [243793920, 244318208)   Aop1   bf16 (256x1024)
//   [244318208, 244334592)   s0     f32 (256x16)
//   [244334592, 244350976)   s1     f32 (256x16)  [memset 0 each call]
//   [244350976, 244367360)   s2     f32 (256x16)  [zeroed by step t=0]
//   [244367360, 245415936)   c_ws   f32 (256x1024)
// ---------------------------------------------------------------------------
extern "C" void kernel_launch(void* const* d_in, const int* in_sizes, int n_in,
                              void* d_out, int out_size, void* d_ws, size_t ws_size,
                              hipStream_t stream) {
  const float* x     = (const float*)d_in[0];
  const float* A     = (const float*)d_in[1];
  const float* Wx    = (const float*)d_in[2];
  const float* Wh    = (const float*)d_in[3];
  const float* Wattn = (const float*)d_in[4];
  const float* bias  = (const float*)d_in[5];
  float* out = (float*)d_out;
  char* ws = (char*)d_ws;
  bf16* Wh_t   = (bf16*)(ws + 0);
  bf16* Wat_t  = (bf16*)(ws + 8388608);
  bf16* At     = (bf16*)(ws + 16777216);
  bf16* A_bf   = (bf16*)(ws + 25165824);
  bf16* xWx2   = (bf16*)(ws + 33554432);
  bf16* G2     = (bf16*)(ws + 167772160);
  bf16* x_bf   = (bf16*)(ws + 201326592);
  bf16* Wxt    = (bf16*)(ws + 234881024);
  bf16* Aop0   = (bf16*)(ws + 243269632);
  bf16* Aop1   = (bf16*)(ws + 243793920);
  float* s0    = (float*)(ws + 244318208);
  float* s1    = (float*)(ws + 244334592);
  float* s2    = (float*)(ws + 244350976);
  float* c_ws  = (float*)(ws + 244367360);

  hipMemsetAsync(s1, 0, 16384, stream);
  convert_bf<<<8192, 256, 0, stream>>>(x, x_bf);
  convert_bf<<<2048, 256, 0, stream>>>(A, A_bf);
  convert_wt<<<2048, 256, 0, stream>>>(Wx, Wxt);
  convert_wt<<<2048, 256, 0, stream>>>(Wh, Wh_t);
  convert_wt<<<2048, 256, 0, stream>>>(Wattn, Wat_t);
  gemm128<0><<<4096, 256, 0, stream>>>(x_bf, Wxt, xWx2);  // xWx2 = x @ Wx
  transpose_A<<<256, 1024, 0, stream>>>(A, At);
  gemm128<1><<<1024, 256, 0, stream>>>(At, Wat_t, G2);    // G2 = A^T @ Wattn
  init_kernel<<<256, 1024, 0, stream>>>(A, c_ws, Aop0, s0);
  for (int t = 0; t < TS; ++t) {
    float* scur = (t % 3 == 0) ? s0 : (t % 3 == 1) ? s1 : s2;
    float* snxt = (t % 3 == 0) ? s1 : (t % 3 == 1) ? s2 : s0;
    float* szro = (t % 3 == 0) ? s2 : (t % 3 == 1) ? s0 : s1;
    step_kernel<<<512, 512, 0, stream>>>((t & 1) ? Aop1 : Aop0,
                                         (t & 1) ? Aop0 : Aop1, Wh_t, xWx2, G2,
                                         scur, snxt, szro, bias, A_bf, c_ws,
                                         out, t);
  }
}